// Round 1
// 1894.695 us; speedup vs baseline: 1.0589x; 1.0589x over previous
//
#include <hip/hip_runtime.h>

// CrossAttention on MI355X (gfx950). Inputs/outputs fp32 (per reference);
// internal compute bf16 MFMA with fp32 accumulation.
// Pipeline: transpose+cast weights -> LN(latent)->bf16 -> Q GEMM ->
// per-batch-group { LN(kv)->bf16 -> K GEMM -> V GEMM (transposed store) ->
// flash attention } -> O GEMM (fp32 out).
// This rev: (1) gemm_bt staging via __builtin_amdgcn_global_load_lds width=16
// (m97 structure, ~874 TF class); (2) attn_fwd 512 threads / 8 waves,
// two 4-wave groups split the key range (8192 each), reg-prefetch staging
// (T14), no mid-loop barrier, in-LDS (m,l,O) merge at the end.
// ws (bf16): WtQ 1M | WtK .75M | WtV .75M | WtO 1M | Aq 4M | Qbuf 4M |
// Obuf 4M | group{ Akv b*12.6M | K b*16.8M | Vt b*16.8M }, b in {8,4,2,1}.

typedef __bf16 bf16x8 __attribute__((ext_vector_type(8)));
typedef float f32x4 __attribute__((ext_vector_type(4)));
typedef unsigned short us4 __attribute__((ext_vector_type(4)));
typedef unsigned int u32;
typedef unsigned short u16;

#define MFMA_BF16(a, b, c) __builtin_amdgcn_mfma_f32_16x16x32_bf16(a, b, c, 0, 0, 0)

__device__ __forceinline__ u16 f2b(float f) {
    u32 x = __builtin_bit_cast(u32, f);
    x += 0x7fffu + ((x >> 16) & 1u);
    return (u16)(x >> 16);
}

typedef const __attribute__((address_space(1))) unsigned int gl_u32;
typedef __attribute__((address_space(3))) unsigned int lds_u32;

// async global->LDS, 16B per lane. LDS dest must be linear in lane id.
__device__ __forceinline__ void g2l16(const u16* g, u16* l) {
    __builtin_amdgcn_global_load_lds((gl_u32*)g, (lds_u32*)l, 16, 0, 0);
}

// ------------- transpose+cast fp32 [R][C] -> bf16 [C][R] (weights) ----------
__global__ void transpose_f32_bf16(const float* __restrict__ in,
                                   u16* __restrict__ out, int R, int C) {
    __shared__ u16 t[32][33];
    int tx = threadIdx.x, ty = threadIdx.y;
    int bx = blockIdx.x * 32, by = blockIdx.y * 32;
#pragma unroll
    for (int j = 0; j < 4; j++)
        t[ty + j * 8][tx] = f2b(in[(long)(by + ty + j * 8) * C + bx + tx]);
    __syncthreads();
#pragma unroll
    for (int j = 0; j < 4; j++)
        out[(long)(bx + ty + j * 8) * R + by + tx] = t[tx][ty + j * 8];
}

// ------------- LayerNorm rows: fp32 in -> bf16 out, fp32 stats --------------
__global__ __launch_bounds__(256) void ln_rows(const float* __restrict__ x,
                                               const float* __restrict__ g,
                                               const float* __restrict__ bt,
                                               u16* __restrict__ y, int C) {
    long row = blockIdx.x;
    int tid = threadIdx.x;
    const float4* xf = (const float4*)(x + row * C);
    int C4 = C >> 2;
    float s = 0.f, ss = 0.f;
    for (int i = tid; i < C4; i += 256) {
        float4 v = xf[i];
        s += v.x + v.y + v.z + v.w;
        ss += v.x * v.x + v.y * v.y + v.z * v.z + v.w * v.w;
    }
#pragma unroll
    for (int off = 1; off < 64; off <<= 1) {
        s += __shfl_xor(s, off);
        ss += __shfl_xor(ss, off);
    }
    __shared__ float red[2][4];
    int wave = tid >> 6;
    if ((tid & 63) == 0) { red[0][wave] = s; red[1][wave] = ss; }
    __syncthreads();
    s = red[0][0] + red[0][1] + red[0][2] + red[0][3];
    ss = red[1][0] + red[1][1] + red[1][2] + red[1][3];
    float inv = 1.f / (float)C;
    float mu = s * inv;
    float var = ss * inv - mu * mu;
    float rstd = rsqrtf(var + 1e-5f);
    const float4* gf = (const float4*)g;
    const float4* bf_ = (const float4*)bt;
    for (int i = tid; i < C4; i += 256) {
        float4 v = xf[i], gv = gf[i], bv = bf_[i];
        us4 pk;
        pk[0] = f2b((v.x - mu) * rstd * gv.x + bv.x);
        pk[1] = f2b((v.y - mu) * rstd * gv.y + bv.y);
        pk[2] = f2b((v.z - mu) * rstd * gv.z + bv.z);
        pk[3] = f2b((v.w - mu) * rstd * gv.w + bv.w);
        *(us4*)&y[row * C + i * 4] = pk;
    }
}

// ------------- GEMM: C[M,1024] = A[M,Kd] @ Bt[1024,Kd]^T --------------------
// A, Bt are [rows][Kd] bf16 row-major (Bt = pre-transposed weight).
// Staging via global_load_lds (async, 16B/lane); As layout is lane-linear:
// byte offset = wave*1024 + lane*16.
template <int VSTORE, int F32OUT>
__global__ __launch_bounds__(256, 2) void gemm_bt(const u16* __restrict__ A,
                                                  const u16* __restrict__ Bt,
                                                  void* __restrict__ Cv, int Kd) {
    __shared__ u16 As[128][32];
    __shared__ u16 Bs[128][32];
    int tid = threadIdx.x;
    int lane = tid & 63, wave = tid >> 6;
    int l15 = lane & 15, quad = lane >> 4;
    int wm = (wave >> 1) << 6, wn = (wave & 1) << 6;
    long m0 = (long)blockIdx.y << 7;
    int n0 = blockIdx.x << 7;
    int r0 = tid >> 2, sg = (tid & 3) << 3;
    const u16* a0 = A + (m0 + r0) * Kd + sg;
    const u16* a1 = a0 + (long)64 * Kd;
    const u16* bp0 = Bt + (long)(n0 + r0) * Kd + sg;
    const u16* bp1 = bp0 + (long)64 * Kd;
    u16* As0 = &As[r0][sg];
    u16* As1 = &As[r0 + 64][sg];
    u16* Bs0 = &Bs[r0][sg];
    u16* Bs1 = &Bs[r0 + 64][sg];
    f32x4 acc[4][4] = {};
    for (int k0 = 0; k0 < Kd; k0 += 32) {
        g2l16(a0 + k0, As0);
        g2l16(a1 + k0, As1);
        g2l16(bp0 + k0, Bs0);
        g2l16(bp1 + k0, Bs1);
        __syncthreads();
        bf16x8 af[4], bf[4];
#pragma unroll
        for (int mt = 0; mt < 4; mt++)
            af[mt] = *(const bf16x8*)&As[wm + mt * 16 + l15][quad * 8];
#pragma unroll
        for (int nt = 0; nt < 4; nt++)
            bf[nt] = *(const bf16x8*)&Bs[wn + nt * 16 + l15][quad * 8];
#pragma unroll
        for (int mt = 0; mt < 4; mt++)
#pragma unroll
            for (int nt = 0; nt < 4; nt++)
                acc[mt][nt] = MFMA_BF16(af[mt], bf[nt], acc[mt][nt]);
        __syncthreads();
    }
    // C/D layout: col = lane&15, row = quad*4 + reg
#pragma unroll
    for (int mt = 0; mt < 4; mt++) {
#pragma unroll
        for (int nt = 0; nt < 4; nt++) {
            int col = n0 + wn + nt * 16 + l15;
            long rowb = m0 + wm + mt * 16 + quad * 4;
            if constexpr (VSTORE) {
                u16* C = (u16*)Cv;
                int bl = (int)(rowb >> 14);
                int key = (int)(rowb & 16383);
                us4 pk;
#pragma unroll
                for (int r = 0; r < 4; r++) pk[r] = f2b(acc[mt][nt][r]);
                *(us4*)&C[((long)(bl * 1024 + col) << 14) + key] = pk;
            } else if constexpr (F32OUT) {
                float* C = (float*)Cv;
#pragma unroll
                for (int r = 0; r < 4; r++)
                    C[(rowb + r) * 1024 + col] = acc[mt][nt][r];
            } else {
                u16* C = (u16*)Cv;
#pragma unroll
                for (int r = 0; r < 4; r++)
                    C[(rowb + r) * 1024 + col] = f2b(acc[mt][nt][r]);
            }
        }
    }
}

// ------------- Flash attention ---------------------------------------------
// Block: one (bl, h, 128-q tile); 512 threads = 8 waves = 2 waves/SIMD.
// Waves 0-3 (group 0) process keys [0,8192); waves 4-7 (group 1) keys
// [8192,16384). Each wave owns 32 q rows. Per group: single-buffered K/V
// LDS tile (64 keys), register-prefetch of the next tile issued before
// compute (T14). End: groups merge (m,l,O) via LDS.
// LDS map (108544 B):
//   [0,36864)       Pw: 8 waves x [32][72] u16 (P^T scratch; m_s/l_s reuse)
//   [36864,71680)   K tiles: group g at +g*17408, [64][136] u16
//                   (Qs [128][136] overlays this region during prologue;
//                    O1 [128][132] f32 overlays K+V regions during merge)
//   [71680,108544)  V tiles: group g at +g*18432, [128][72] u16
__global__ __launch_bounds__(512, 2) void attn_fwd(const u16* __restrict__ Qb,
                                                   const u16* __restrict__ Kb,
                                                   const u16* __restrict__ Vt,
                                                   u16* __restrict__ Ob, int b0) {
    int h = blockIdx.x & 7, bl = blockIdx.x >> 3, qblk = blockIdx.y;
    int tid = threadIdx.x, lane = tid & 63, wave = tid >> 6;
    int l15 = lane & 15, quad = lane >> 4;
    int grp = wave >> 2;
    int wq = (wave & 3) << 5;
    int gtid = tid & 255;

    __shared__ __align__(16) char smem[108544];
    u16(*Pw)[72] = (u16(*)[72])(smem + wave * (32 * 72 * 2));
    u16(*Qs)[136] = (u16(*)[136])(smem + 36864);
    u16(*Ks)[136] = (u16(*)[136])(smem + 36864 + grp * 17408);
    u16(*Vs)[72] = (u16(*)[72])(smem + 71680 + grp * 18432);

    long qrow0 = (long)(b0 + bl) * 512 + qblk * 128;
    // ---- Q -> LDS -> regs ----
#pragma unroll
    for (int i = 0; i < 4; i++) {
        int L = tid + i * 512;
        int row = L >> 4, seg = L & 15;
        *(uint4*)&Qs[row][seg * 8] =
            *(const uint4*)&Qb[(qrow0 + row) * 1024 + h * 128 + seg * 8];
    }
    __syncthreads();
    bf16x8 qf[2][4];
#pragma unroll
    for (int nt = 0; nt < 2; nt++)
#pragma unroll
        for (int kc = 0; kc < 4; kc++)
            qf[nt][kc] = *(const bf16x8*)&Qs[wq + nt * 16 + l15][kc * 32 + quad * 8];
    __syncthreads();  // Q region reused for K below

    const u16* Kg = Kb + ((long)bl * 16384 + (long)grp * 8192) * 1024 + h * 128;
    const u16* Vg = Vt + ((long)(bl * 1024 + h * 128)) * 16384 + grp * 8192;

    uint4 kr[4], vr[4];
    // prologue: stage tile 0
#pragma unroll
    for (int i = 0; i < 4; i++) {
        int L = gtid + i * 256;
        kr[i] = *(const uint4*)&Kg[(long)(L >> 4) * 1024 + (L & 15) * 8];
        vr[i] = *(const uint4*)&Vg[(long)(L >> 3) * 16384 + (L & 7) * 8];
    }
#pragma unroll
    for (int i = 0; i < 4; i++) {
        int L = gtid + i * 256;
        *(uint4*)&Ks[L >> 4][(L & 15) * 8] = kr[i];
        *(uint4*)&Vs[L >> 3][(L & 7) * 8] = vr[i];
    }
    __syncthreads();

    f32x4 o[2][8] = {};
    float m_run[2] = {-1e30f, -1e30f};
    float l_run[2] = {0.f, 0.f};
    const float scl = 0.08838834764831845f;  // 1/sqrt(128)

    for (int it = 0; it < 128; it++) {
        int kv0 = it << 6;
        // issue next-tile global loads early; consumed after the barrier
        if (it < 127) {
#pragma unroll
            for (int i = 0; i < 4; i++) {
                int L = gtid + i * 256;
                kr[i] = *(const uint4*)&Kg[(long)(kv0 + 64 + (L >> 4)) * 1024 + (L & 15) * 8];
                vr[i] = *(const uint4*)&Vg[(long)(L >> 3) * 16384 + kv0 + 64 + (L & 7) * 8];
            }
        }

        f32x4 s[4][2] = {};
#pragma unroll
        for (int kc = 0; kc < 4; kc++) {
            bf16x8 kf[4];
#pragma unroll
            for (int mt = 0; mt < 4; mt++)
                kf[mt] = *(const bf16x8*)&Ks[mt * 16 + l15][kc * 32 + quad * 8];
#pragma unroll
            for (int mt = 0; mt < 4; mt++) {
                s[mt][0] = MFMA_BF16(kf[mt], qf[0][kc], s[mt][0]);
                s[mt][1] = MFMA_BF16(kf[mt], qf[1][kc], s[mt][1]);
            }
        }

#pragma unroll
        for (int nt = 0; nt < 2; nt++) {
            float pm = -1e30f;
#pragma unroll
            for (int mt = 0; mt < 4; mt++)
#pragma unroll
                for (int r = 0; r < 4; r++) pm = fmaxf(pm, s[mt][nt][r]);
            pm = fmaxf(pm, __shfl_xor(pm, 16));
            pm = fmaxf(pm, __shfl_xor(pm, 32));
            float mnew = fmaxf(m_run[nt], pm);
            float alpha = __expf((m_run[nt] - mnew) * scl);
            m_run[nt] = mnew;
            float mc = mnew * scl;
            float psum = 0.f;
#pragma unroll
            for (int mt = 0; mt < 4; mt++) {
                us4 pk;
#pragma unroll
                for (int r = 0; r < 4; r++) {
                    float p = __expf(s[mt][nt][r] * scl - mc);
                    psum += p;
                    pk[r] = f2b(p);
                }
                *(us4*)&Pw[nt * 16 + l15][mt * 16 + quad * 4] = pk;
            }
            psum += __shfl_xor(psum, 16);
            psum += __shfl_xor(psum, 32);
            l_run[nt] = l_run[nt] * alpha + psum;
            float af_[4];
#pragma unroll
            for (int r = 0; r < 4; r++) af_[r] = __shfl(alpha, quad * 4 + r);
#pragma unroll
            for (int n = 0; n < 8; n++)
#pragma unroll
                for (int r = 0; r < 4; r++) o[nt][n][r] *= af_[r];
        }
        // Pw is wave-private: lgkmcnt ordering suffices, no barrier needed.

#pragma unroll
        for (int kc = 0; kc < 2; kc++) {
            bf16x8 pf0 = *(const bf16x8*)&Pw[l15][kc * 32 + quad * 8];
            bf16x8 pf1 = *(const bf16x8*)&Pw[16 + l15][kc * 32 + quad * 8];
#pragma unroll
            for (int n = 0; n < 8; n++) {
                bf16x8 vf = *(const bf16x8*)&Vs[n * 16 + l15][kc * 32 + quad * 8];
                o[0][n] = MFMA_BF16(pf0, vf, o[0][n]);
                o[1][n] = MFMA_BF16(pf1, vf, o[1][n]);
            }
        }
        __syncthreads();  // all waves done reading K/V tiles
        if (it < 127) {
#pragma unroll
            for (int i = 0; i < 4; i++) {
                int L = gtid + i * 256;
                *(uint4*)&Ks[L >> 4][(L & 15) * 8] = kr[i];
                *(uint4*)&Vs[L >> 3][(L & 7) * 8] = vr[i];
            }
        }
        __syncthreads();  // staged tile visible for next iter
    }

    // ---- merge the two key-range groups ----
    __syncthreads();
    float* m_s = (float*)smem;              // [128]
    float* l_s = (float*)(smem + 512);      // [128]
    float(*O1)[132] = (float(*)[132])(smem + 36864);  // 128x132 f32 = 67584 B
    if (grp == 1) {
        if (quad == 0) {
#pragma unroll
            for (int nt = 0; nt < 2; nt++) {
                m_s[wq + nt * 16 + l15] = m_run[nt];
                l_s[wq + nt * 16 + l15] = l_run[nt];
            }
        }
#pragma unroll
        for (int nt = 0; nt < 2; nt++)
#pragma unroll
            for (int n = 0; n < 8; n++)
#pragma unroll
                for (int r = 0; r < 4; r++)
                    O1[wq + nt * 16 + quad * 4 + r][n * 16 + l15] = o[nt][n][r];
    }
    __syncthreads();
    if (grp == 0) {
        long orow0 = qrow0 + wq;
#pragma unroll
        for (int nt = 0; nt < 2; nt++) {
            int q = wq + nt * 16 + l15;
            float m1 = m_s[q], l1v = l_s[q];
            float M = fmaxf(m_run[nt], m1);
            float a0 = __expf((m_run[nt] - M) * scl);
            float a1 = __expf((m1 - M) * scl);
            float L = l_run[nt] * a0 + l1v * a1;
            float a0r[4], a1r[4], li[4];
#pragma unroll
            for (int r = 0; r < 4; r++) {
                int sl = quad * 4 + r;
                a0r[r] = __shfl(a0, sl);
                a1r[r] = __shfl(a1, sl);
                li[r] = 1.f / __shfl(L, sl);
            }
#pragma unroll
            for (int n = 0; n < 8; n++) {
                int col = h * 128 + n * 16 + l15;
#pragma unroll
                for (int r = 0; r < 4; r++) {
                    float v = (o[nt][n][r] * a0r[r] +
                               O1[wq + nt * 16 + quad * 4 + r][n * 16 + l15] * a1r[r]) *
                              li[r];
                    Ob[(orow0 + nt * 16 + quad * 4 + r) * 1024 + col] = f2b(v);
                }
            }
        }
    }
}

// ---------------------------------------------------------------------------
extern "C" void kernel_launch(void* const* d_in, const int* in_sizes, int n_in,
                              void* d_out, int out_size, void* d_ws, size_t ws_size,
                              hipStream_t stream) {
    const float* latent = (const float*)d_in[0];
    const float* inpkv = (const float*)d_in[1];
    const float* W_Q = (const float*)d_in[2];
    const float* W_K = (const float*)d_in[3];
    const float* W_V = (const float*)d_in[4];
    const float* W_O = (const float*)d_in[5];
    const float* g_lat = (const float*)d_in[6];
    const float* b_lat = (const float*)d_in[7];
    const float* g_in = (const float*)d_in[8];
    const float* b_in = (const float*)d_in[9];
    float* out = (float*)d_out;

    u16* ws = (u16*)d_ws;
    u16* WtQ = ws;  ws += 1024L * 1024;
    u16* WtK = ws;  ws += 1024L * 768;
    u16* WtV = ws;  ws += 1024L * 768;
    u16* WtO = ws;  ws += 1024L * 1024;
    u16* Aq = ws;   ws += 4096L * 1024;
    u16* Qbuf = ws; ws += 4096L * 1024;
    u16* Obuf = ws; ws += 4096L * 1024;
    size_t fixed_bytes = (size_t)((char*)ws - (char*)d_ws);
    size_t per_batch = (size_t)(16384L * 768 + 2 * 16384L * 1024) * 2;
    int bstep = 1;
    for (int b = 8; b >= 1; b >>= 1)
        if (ws_size >= fixed_bytes + (size_t)b * per_batch) { bstep = b; break; }
    u16* Akv = ws;
    u16* Kbf = Akv + (long)bstep * 16384 * 768;
    u16* Vtb = Kbf + (long)bstep * 16384 * 1024;

    dim3 t328(32, 8);
    transpose_f32_bf16<<<dim3(32, 32), t328, 0, stream>>>(W_Q, WtQ, 1024, 1024);
    transpose_f32_bf16<<<dim3(32, 24), t328, 0, stream>>>(W_K, WtK, 768, 1024);
    transpose_f32_bf16<<<dim3(32, 24), t328, 0, stream>>>(W_V, WtV, 768, 1024);
    transpose_f32_bf16<<<dim3(32, 32), t328, 0, stream>>>(W_O, WtO, 1024, 1024);

    ln_rows<<<4096, 256, 0, stream>>>(latent, g_lat, b_lat, Aq, 1024);
    gemm_bt<0, 0><<<dim3(8, 32), 256, 0, stream>>>(Aq, WtQ, Qbuf, 1024);

    for (int b0 = 0; b0 < 8; b0 += bstep) {
        ln_rows<<<bstep * 16384, 256, 0, stream>>>(inpkv + (long)b0 * 16384 * 768,
                                                   g_in, b_in, Akv, 768);
        gemm_bt<0, 0><<<dim3(8, bstep * 128), 256, 0, stream>>>(Akv, WtK, Kbf, 768);
        gemm_bt<1, 0><<<dim3(8, bstep * 128), 256, 0, stream>>>(Akv, WtV, Vtb, 768);
        attn_fwd<<<dim3(bstep * 8, 4), 512, 0, stream>>>(Qbuf, Kbf, Vtb, Obuf, b0);
    }
    gemm_bt<0, 1><<<dim3(8, 32), 256, 0, stream>>>(Obuf, WtO, out, 1024);
}

// Round 2
// 1575.477 us; speedup vs baseline: 1.2734x; 1.2026x over previous
//
#include <hip/hip_runtime.h>

// CrossAttention on MI355X (gfx950). Inputs/outputs fp32 (per reference);
// internal compute bf16 MFMA with fp32 accumulation.
// Pipeline: transpose+cast weights -> LN(latent)->bf16 -> Q GEMM ->
// per-batch-group { LN(kv)->bf16 -> K GEMM -> V GEMM (transposed store) ->
// flash attention (kv split across blocks) -> merge } -> O GEMM (fp32 out).
// This rev: attn v3 -- one shared K/V double-buffered LDS tile per block
// (staged via global_load_lds with pre-swizzled global source; XOR bank
// swizzle slot^=row&7), 8 waves x 32q = 256-q tile, keys split 2-way across
// blocks with a tiny merge kernel (partials alias the dead Akv region).
// One barrier per KV iteration. GEMMs get an XCD-aware bid swizzle so the
// 8 N-blocks sharing an A-panel land on one XCD's L2.

typedef __bf16 bf16x8 __attribute__((ext_vector_type(8)));
typedef float f32x4 __attribute__((ext_vector_type(4)));
typedef unsigned short us4 __attribute__((ext_vector_type(4)));
typedef unsigned int u32;
typedef unsigned short u16;

#define MFMA_BF16(a, b, c) __builtin_amdgcn_mfma_f32_16x16x32_bf16(a, b, c, 0, 0, 0)

__device__ __forceinline__ u16 f2b(float f) {
    u32 x = __builtin_bit_cast(u32, f);
    x += 0x7fffu + ((x >> 16) & 1u);
    return (u16)(x >> 16);
}

typedef const __attribute__((address_space(1))) unsigned int gl_u32;
typedef __attribute__((address_space(3))) unsigned int lds_u32;

// async global->LDS, 16B per lane. LDS dest must be linear in lane id.
__device__ __forceinline__ void g2l16(const u16* g, u16* l) {
    __builtin_amdgcn_global_load_lds((gl_u32*)g, (lds_u32*)l, 16, 0, 0);
}

// ------------- transpose+cast fp32 [R][C] -> bf16 [C][R] (weights) ----------
__global__ void transpose_f32_bf16(const float* __restrict__ in,
                                   u16* __restrict__ out, int R, int C) {
    __shared__ u16 t[32][33];
    int tx = threadIdx.x, ty = threadIdx.y;
    int bx = blockIdx.x * 32, by = blockIdx.y * 32;
#pragma unroll
    for (int j = 0; j < 4; j++)
        t[ty + j * 8][tx] = f2b(in[(long)(by + ty + j * 8) * C + bx + tx]);
    __syncthreads();
#pragma unroll
    for (int j = 0; j < 4; j++)
        out[(long)(bx + ty + j * 8) * R + by + tx] = t[tx][ty + j * 8];
}

// ------------- LayerNorm rows: fp32 in -> bf16 out, fp32 stats --------------
__global__ __launch_bounds__(256) void ln_rows(const float* __restrict__ x,
                                               const float* __restrict__ g,
                                               const float* __restrict__ bt,
                                               u16* __restrict__ y, int C) {
    long row = blockIdx.x;
    int tid = threadIdx.x;
    const float4* xf = (const float4*)(x + row * C);
    int C4 = C >> 2;
    float s = 0.f, ss = 0.f;
    for (int i = tid; i < C4; i += 256) {
        float4 v = xf[i];
        s += v.x + v.y + v.z + v.w;
        ss += v.x * v.x + v.y * v.y + v.z * v.z + v.w * v.w;
    }
#pragma unroll
    for (int off = 1; off < 64; off <<= 1) {
        s += __shfl_xor(s, off);
        ss += __shfl_xor(ss, off);
    }
    __shared__ float red[2][4];
    int wave = tid >> 6;
    if ((tid & 63) == 0) { red[0][wave] = s; red[1][wave] = ss; }
    __syncthreads();
    s = red[0][0] + red[0][1] + red[0][2] + red[0][3];
    ss = red[1][0] + red[1][1] + red[1][2] + red[1][3];
    float inv = 1.f / (float)C;
    float mu = s * inv;
    float var = ss * inv - mu * mu;
    float rstd = rsqrtf(var + 1e-5f);
    const float4* gf = (const float4*)g;
    const float4* bf_ = (const float4*)bt;
    for (int i = tid; i < C4; i += 256) {
        float4 v = xf[i], gv = gf[i], bv = bf_[i];
        us4 pk;
        pk[0] = f2b((v.x - mu) * rstd * gv.x + bv.x);
        pk[1] = f2b((v.y - mu) * rstd * gv.y + bv.y);
        pk[2] = f2b((v.z - mu) * rstd * gv.z + bv.z);
        pk[3] = f2b((v.w - mu) * rstd * gv.w + bv.w);
        *(us4*)&y[row * C + i * 4] = pk;
    }
}

// ------------- GEMM: C[M,1024] = A[M,Kd] @ Bt[1024,Kd]^T --------------------
// A, Bt are [rows][Kd] bf16 row-major (Bt = pre-transposed weight).
// Staging via global_load_lds (async, 16B/lane); As layout is lane-linear.
// bid swizzle: the 8 N-blocks of one m-panel land on ONE XCD (bid%8 picks
// the XCD under round-robin dispatch) so the shared A-panel stays in its L2.
template <int VSTORE, int F32OUT>
__global__ __launch_bounds__(256, 2) void gemm_bt(const u16* __restrict__ A,
                                                  const u16* __restrict__ Bt,
                                                  void* __restrict__ Cv, int Kd) {
    __shared__ u16 As[128][32];
    __shared__ u16 Bs[128][32];
    int tid = threadIdx.x;
    int lane = tid & 63, wave = tid >> 6;
    int l15 = lane & 15, quad = lane >> 4;
    int wm = (wave >> 1) << 6, wn = (wave & 1) << 6;
    // XCD swizzle (gridDim.x==8, gridDim.y % 8 == 0 always here)
    int bid = blockIdx.x + (blockIdx.y << 3);
    int xcd = bid & 7, j = bid >> 3;
    int n0 = (j & 7) << 7;
    long m0 = (long)(((j >> 3) << 3) + xcd) << 7;
    int r0 = tid >> 2, sg = (tid & 3) << 3;
    const u16* a0 = A + (m0 + r0) * Kd + sg;
    const u16* a1 = a0 + (long)64 * Kd;
    const u16* bp0 = Bt + (long)(n0 + r0) * Kd + sg;
    const u16* bp1 = bp0 + (long)64 * Kd;
    u16* As0 = &As[r0][sg];
    u16* As1 = &As[r0 + 64][sg];
    u16* Bs0 = &Bs[r0][sg];
    u16* Bs1 = &Bs[r0 + 64][sg];
    f32x4 acc[4][4] = {};
    for (int k0 = 0; k0 < Kd; k0 += 32) {
        g2l16(a0 + k0, As0);
        g2l16(a1 + k0, As1);
        g2l16(bp0 + k0, Bs0);
        g2l16(bp1 + k0, Bs1);
        __syncthreads();
        bf16x8 af[4], bf[4];
#pragma unroll
        for (int mt = 0; mt < 4; mt++)
            af[mt] = *(const bf16x8*)&As[wm + mt * 16 + l15][quad * 8];
#pragma unroll
        for (int nt = 0; nt < 4; nt++)
            bf[nt] = *(const bf16x8*)&Bs[wn + nt * 16 + l15][quad * 8];
#pragma unroll
        for (int mt = 0; mt < 4; mt++)
#pragma unroll
            for (int nt = 0; nt < 4; nt++)
                acc[mt][nt] = MFMA_BF16(af[mt], bf[nt], acc[mt][nt]);
        __syncthreads();
    }
    // C/D layout: col = lane&15, row = quad*4 + reg
#pragma unroll
    for (int mt = 0; mt < 4; mt++) {
#pragma unroll
        for (int nt = 0; nt < 4; nt++) {
            int col = n0 + wn + nt * 16 + l15;
            long rowb = m0 + wm + mt * 16 + quad * 4;
            if constexpr (VSTORE) {
                u16* C = (u16*)Cv;
                int bl = (int)(rowb >> 14);
                int key = (int)(rowb & 16383);
                us4 pk;
#pragma unroll
                for (int r = 0; r < 4; r++) pk[r] = f2b(acc[mt][nt][r]);
                *(us4*)&C[((long)(bl * 1024 + col) << 14) + key] = pk;
            } else if constexpr (F32OUT) {
                float* C = (float*)Cv;
#pragma unroll
                for (int r = 0; r < 4; r++)
                    C[(rowb + r) * 1024 + col] = acc[mt][nt][r];
            } else {
                u16* C = (u16*)Cv;
#pragma unroll
                for (int r = 0; r < 4; r++)
                    C[(rowb + r) * 1024 + col] = f2b(acc[mt][nt][r]);
            }
        }
    }
}

// ------------- Flash attention (v3) ----------------------------------------
// Block: (bl, h, qtile[0..1], kvhalf[0..1]); 512 threads = 8 waves, each wave
// owns 32 q rows of a 256-q tile. ONE shared K/V tile pair (64 keys),
// double-buffered, staged by all 8 waves via global_load_lds with
// pre-swizzled global source (LDS linear, reads XOR-swizzled: slot^=row&7).
// One barrier per iteration. Partial (O,m,l) written to workspace; merge
// kernel combines the two kv halves.
// LDS (98304 B): KB 2x[64][128] (32K) | VB 2x[128][64] (32K) |
//                Pw 8 waves x [32][64] swizzled (32K). Qs overlays prologue.
__global__ __launch_bounds__(512, 2) void attn_fwd(const u16* __restrict__ Qb,
                                                   const u16* __restrict__ Kb,
                                                   const u16* __restrict__ Vt,
                                                   float* __restrict__ Opart,
                                                   float* __restrict__ Ml, int b0) {
    int h = blockIdx.x & 7, bl = blockIdx.x >> 3;
    int qtile = blockIdx.y >> 1, half = blockIdx.y & 1;
    int rows = gridDim.x << 6;  // bstep*512
    int tid = threadIdx.x, lane = tid & 63, wave = tid >> 6;
    int l15 = lane & 15, quad = lane >> 4;
    int l7 = l15 & 7;

    __shared__ __align__(16) char smem[98304];
    u16* KB = (u16*)smem;                            // [2][8192]
    u16* VB = (u16*)(smem + 32768);                  // [2][8192]
    u16* Pw = (u16*)(smem + 65536) + wave * 2048;    // [32][64] swizzled
    u16(*Qs)[136] = (u16(*)[136])smem;               // prologue overlay

    long qrow0 = (long)(b0 + bl) * 512 + qtile * 256;
    // ---- Q -> LDS -> regs (256 rows x 128) ----
#pragma unroll
    for (int i = 0; i < 8; i++) {
        int L = tid + i * 512;
        int row = L >> 4, seg = L & 15;
        *(uint4*)&Qs[row][seg * 8] =
            *(const uint4*)&Qb[(qrow0 + row) * 1024 + h * 128 + seg * 8];
    }
    __syncthreads();
    bf16x8 qf[2][4];
#pragma unroll
    for (int nt = 0; nt < 2; nt++)
#pragma unroll
        for (int kc = 0; kc < 4; kc++)
            qf[nt][kc] = *(const bf16x8*)&Qs[wave * 32 + nt * 16 + l15][kc * 32 + quad * 8];
    __syncthreads();  // Q region reused for K/V tiles below

    const u16* Kg = Kb + ((long)bl * 16384 + half * 8192) * 1024 + h * 128;
    const u16* Vg = Vt + ((long)(bl * 1024 + h * 128)) * 16384 + half * 8192;

    // per-thread staging offsets; source is pre-swizzled so the linear
    // global_load_lds write lands at slot = seg ^ (row&7).
    int S0 = tid, S1 = tid + 512;
    int kO0 = (S0 >> 4) * 1024 + (((S0 & 15) ^ ((S0 >> 4) & 7)) << 3);
    int kO1 = (S1 >> 4) * 1024 + (((S1 & 15) ^ ((S1 >> 4) & 7)) << 3);
    long vO0 = (long)(S0 >> 3) * 16384 + (((S0 & 7) ^ ((S0 >> 3) & 7)) << 3);
    long vO1 = (long)(S1 >> 3) * 16384 + (((S1 & 7) ^ ((S1 >> 3) & 7)) << 3);

    // stage tile 0 into buf 0
    g2l16(Kg + kO0, KB + S0 * 8);
    g2l16(Kg + kO1, KB + S1 * 8);
    g2l16(Vg + vO0, VB + S0 * 8);
    g2l16(Vg + vO1, VB + S1 * 8);
    __syncthreads();

    f32x4 o[2][8] = {};
    float m_run[2] = {-1e30f, -1e30f};
    float l_run[2] = {0.f, 0.f};
    const float scl = 0.08838834764831845f;  // 1/sqrt(128)

    int cur = 0;
    for (int it = 0; it < 128; it++) {
        const u16* Kc = KB + cur * 8192;
        const u16* Vc = VB + cur * 8192;
        if (it < 127) {  // async prefetch next tile into other buffer
            long kb = (long)(it + 1) << 16;  // (it+1)*64*1024 u16
            int vb = (it + 1) << 6;
            u16* Kn = KB + (cur ^ 1) * 8192;
            u16* Vn = VB + (cur ^ 1) * 8192;
            g2l16(Kg + kb + kO0, Kn + S0 * 8);
            g2l16(Kg + kb + kO1, Kn + S1 * 8);
            g2l16(Vg + vb + vO0, Vn + S0 * 8);
            g2l16(Vg + vb + vO1, Vn + S1 * 8);
        }

        f32x4 s[4][2] = {};
#pragma unroll
        for (int kc = 0; kc < 4; kc++) {
            int ks = (((kc << 2) + quad) ^ l7) << 3;
            bf16x8 kf[4];
#pragma unroll
            for (int mt = 0; mt < 4; mt++)
                kf[mt] = *(const bf16x8*)&Kc[(mt * 16 + l15) * 128 + ks];
#pragma unroll
            for (int mt = 0; mt < 4; mt++) {
                s[mt][0] = MFMA_BF16(kf[mt], qf[0][kc], s[mt][0]);
                s[mt][1] = MFMA_BF16(kf[mt], qf[1][kc], s[mt][1]);
            }
        }

#pragma unroll
        for (int nt = 0; nt < 2; nt++) {
            float pm = -1e30f;
#pragma unroll
            for (int mt = 0; mt < 4; mt++)
#pragma unroll
                for (int r = 0; r < 4; r++) pm = fmaxf(pm, s[mt][nt][r]);
            pm = fmaxf(pm, __shfl_xor(pm, 16));
            pm = fmaxf(pm, __shfl_xor(pm, 32));
            float mnew = fmaxf(m_run[nt], pm);
            float alpha = __expf((m_run[nt] - mnew) * scl);
            m_run[nt] = mnew;
            float mc = mnew * scl;
            float psum = 0.f;
            int pbase = (nt * 16 + l15) * 64 + ((quad & 1) << 2);
#pragma unroll
            for (int mt = 0; mt < 4; mt++) {
                us4 pk;
#pragma unroll
                for (int r = 0; r < 4; r++) {
                    float p = __expf(s[mt][nt][r] * scl - mc);
                    psum += p;
                    pk[r] = f2b(p);
                }
                *(us4*)&Pw[pbase + ((((mt << 1) + (quad >> 1)) ^ l7) << 3)] = pk;
            }
            psum += __shfl_xor(psum, 16);
            psum += __shfl_xor(psum, 32);
            l_run[nt] = l_run[nt] * alpha + psum;
            float af_[4];
#pragma unroll
            for (int r = 0; r < 4; r++) af_[r] = __shfl(alpha, quad * 4 + r);
#pragma unroll
            for (int n = 0; n < 8; n++)
#pragma unroll
                for (int r = 0; r < 4; r++) o[nt][n][r] *= af_[r];
        }
        // Pw is wave-private; in-wave DS ordering suffices.

#pragma unroll
        for (int kc = 0; kc < 2; kc++) {
            int sl = (((kc << 2) + quad) ^ l7) << 3;
            bf16x8 pf0 = *(const bf16x8*)&Pw[l15 * 64 + sl];
            bf16x8 pf1 = *(const bf16x8*)&Pw[(16 + l15) * 64 + sl];
#pragma unroll
            for (int n = 0; n < 8; n++) {
                bf16x8 vf = *(const bf16x8*)&Vc[(n * 16 + l15) * 64 + sl];
                o[0][n] = MFMA_BF16(pf0, vf, o[0][n]);
                o[1][n] = MFMA_BF16(pf1, vf, o[1][n]);
            }
        }
        __syncthreads();  // tile consumed; prefetched writes drained
        cur ^= 1;
    }

    // ---- write partials (unnormalized O, m, l) ----
    long prq = (long)bl * 512 + qtile * 256 + wave * 32;
    float* Oh = Opart + ((long)half * rows) * 1024 + h * 128;
#pragma unroll
    for (int nt = 0; nt < 2; nt++) {
        if (quad == 0) {
            long qi = (long)half * rows + prq + nt * 16 + l15;
            Ml[(qi * 8 + h) * 2] = m_run[nt];
            Ml[(qi * 8 + h) * 2 + 1] = l_run[nt];
        }
#pragma unroll
        for (int n = 0; n < 8; n++)
#pragma unroll
            for (int r = 0; r < 4; r++)
                Oh[(prq + nt * 16 + quad * 4 + r) * 1024 + n * 16 + l15] = o[nt][n][r];
    }
}

// ------------- merge the two kv-half partials -> bf16 Obuf ------------------
__global__ __launch_bounds__(256) void attn_merge(const float* __restrict__ Op,
                                                  const float* __restrict__ Ml,
                                                  u16* __restrict__ Ob, int b0,
                                                  int rows) {
    int pr = blockIdx.x, tid = threadIdx.x;
    const float scl = 0.08838834764831845f;
    long b0r = (long)(b0 * 512 + pr) * 1024;
    long p0 = (long)pr * 1024, p1 = ((long)rows + pr) * 1024;
#pragma unroll
    for (int rep = 0; rep < 4; rep++) {
        int col = tid + rep * 256;
        int h = col >> 7;
        long mi0 = ((long)pr * 8 + h) * 2;
        long mi1 = (((long)rows + pr) * 8 + h) * 2;
        float m0 = Ml[mi0], l0 = Ml[mi0 + 1];
        float m1 = Ml[mi1], l1 = Ml[mi1 + 1];
        float M = fmaxf(m0, m1);
        float a0 = __expf((m0 - M) * scl), a1 = __expf((m1 - M) * scl);
        float v = (Op[p0 + col] * a0 + Op[p1 + col] * a1) / (l0 * a0 + l1 * a1);
        Ob[b0r + col] = f2b(v);
    }
}

// ---------------------------------------------------------------------------
extern "C" void kernel_launch(void* const* d_in, const int* in_sizes, int n_in,
                              void* d_out, int out_size, void* d_ws, size_t ws_size,
                              hipStream_t stream) {
    const float* latent = (const float*)d_in[0];
    const float* inpkv = (const float*)d_in[1];
    const float* W_Q = (const float*)d_in[2];
    const float* W_K = (const float*)d_in[3];
    const float* W_V = (const float*)d_in[4];
    const float* W_O = (const float*)d_in[5];
    const float* g_lat = (const float*)d_in[6];
    const float* b_lat = (const float*)d_in[7];
    const float* g_in = (const float*)d_in[8];
    const float* b_in = (const float*)d_in[9];
    float* out = (float*)d_out;

    u16* ws = (u16*)d_ws;
    u16* WtQ = ws;  ws += 1024L * 1024;
    u16* WtK = ws;  ws += 1024L * 768;
    u16* WtV = ws;  ws += 1024L * 768;
    u16* WtO = ws;  ws += 1024L * 1024;
    u16* Aq = ws;   ws += 4096L * 1024;
    u16* Qbuf = ws; ws += 4096L * 1024;
    u16* Obuf = ws; ws += 4096L * 1024;
    size_t fixed_bytes = (size_t)((char*)ws - (char*)d_ws);
    size_t per_batch = (size_t)(16384L * 768 + 2 * 16384L * 1024) * 2;
    int bstep = 1;
    for (int b = 8; b >= 1; b >>= 1)
        if (ws_size >= fixed_bytes + (size_t)b * per_batch) { bstep = b; break; }
    u16* Akv = ws;
    u16* Kbf = Akv + (long)bstep * 16384 * 768;
    u16* Vtb = Kbf + (long)bstep * 16384 * 1024;
    // Partials alias Akv: Akv is dead once the K/V GEMMs have read it, and
    // is rewritten only at the next loop iteration (stream-ordered).
    int rows = bstep * 512;
    float* Opart = (float*)Akv;                       // [2][rows][1024] f32
    float* Mlp = Opart + (long)2 * rows * 1024;       // [2][rows][8][2] f32

    dim3 t328(32, 8);
    transpose_f32_bf16<<<dim3(32, 32), t328, 0, stream>>>(W_Q, WtQ, 1024, 1024);
    transpose_f32_bf16<<<dim3(32, 24), t328, 0, stream>>>(W_K, WtK, 768, 1024);
    transpose_f32_bf16<<<dim3(32, 24), t328, 0, stream>>>(W_V, WtV, 768, 1024);
    transpose_f32_bf16<<<dim3(32, 32), t328, 0, stream>>>(W_O, WtO, 1024, 1024);

    ln_rows<<<4096, 256, 0, stream>>>(latent, g_lat, b_lat, Aq, 1024);
    gemm_bt<0, 0><<<dim3(8, 32), 256, 0, stream>>>(Aq, WtQ, Qbuf, 1024);

    for (int b0 = 0; b0 < 8; b0 += bstep) {
        ln_rows<<<bstep * 16384, 256, 0, stream>>>(inpkv + (long)b0 * 16384 * 768,
                                                   g_in, b_in, Akv, 768);
        gemm_bt<0, 0><<<dim3(8, bstep * 128), 256, 0, stream>>>(Akv, WtK, Kbf, 768);
        gemm_bt<1, 0><<<dim3(8, bstep * 128), 256, 0, stream>>>(Akv, WtV, Vtb, 768);
        attn_fwd<<<dim3(bstep * 8, 4), 512, 0, stream>>>(Qbuf, Kbf, Vtb, Opart, Mlp, b0);
        attn_merge<<<rows, 256, 0, stream>>>(Opart, Mlp, Obuf, b0, rows);
    }
    gemm_bt<0, 1><<<dim3(8, 32), 256, 0, stream>>>(Obuf, WtO, out, 1024);
}